// Round 6
// baseline (188.035 us; speedup 1.0000x reference)
//
#include <hip/hip_runtime.h>
#include <stdint.h>

// ContrastiveLoss: mean over all pairs of (same-label ? d2 : relu(1-dist)^2)
// z: [8192,128] fp32, labels: [8192] int32. Output: 1 fp32 scalar.
//
// R6: revert to R4's proven 512-thr/8-wave/2x4-frag structure (R5's 4x4 acc
// = 64 AGPRs starved VGPRs -> 124 MB scratch spill). Fixes from counters:
//  - SQ_LDS_BANK_CONFLICT was 64 cyc/wave in R4/R5: 128B rows = 32 banks, so
//    16B-granule reads alias lanes lc/lc+8. Fix: 8B granules, slot =
//    ((q<<2)|ks) ^ (row&15), baked into zb by prep -> staging is a pure
//    linear copy and ds_read_b64 frag reads hit all 32 banks exactly once.
//  - Deferred single wave-vote epilogue (acc 2x4 = 32 regs, safe).
//  - Final reduction fused via device-scope ticket (reduce_kernel dropped).
//  - __launch_bounds__(512,6): ~74 regs est vs 85 cap -> 3 blocks/CU.

#define NROWS 8192
#define DIMK  128
#define NB    64                     // 8192 / 128
#define NBLK  (NB * (NB + 1) / 2)    // 2080 upper-triangle blocks

typedef __attribute__((ext_vector_type(4))) float f32x4;

#define AS_GLOBAL __attribute__((address_space(1)))
#define AS_LDS    __attribute__((address_space(3)))

// Convert z -> fp8 e4m3 with granule-swizzled rows: logical k lives in
// granule g = ((k>>3)&3)<<2 | (k>>5) (the 8B MFMA operand for quad q, step
// ks), stored at byte pos ((g ^ (row&15)) << 3) + (k&7). Dot-invariant.
// Also: per-row sum of squares of ROUNDED values (diagonal d2 == 0 exactly),
// and zero the ticket counter.
__global__ __launch_bounds__(256) void prep_kernel(
    const float* __restrict__ z, unsigned char* __restrict__ zb,
    float* __restrict__ sq, unsigned int* __restrict__ counter) {
  if (blockIdx.x == 0 && threadIdx.x == 0) *counter = 0;
  int tid = threadIdx.x;
  int row = (blockIdx.x << 3) + (tid >> 5);          // 8 rows per block
  int c32 = tid & 31;                                // 32 lanes per row
  float4 x = ((const float4*)(z + (size_t)row * DIMK))[c32];
  int u = __builtin_amdgcn_cvt_pk_fp8_f32(x.x, x.y, 0, false);
  u     = __builtin_amdgcn_cvt_pk_fp8_f32(x.z, x.w, u, true);
  float r0 = __builtin_amdgcn_cvt_f32_fp8(u, 0);
  float r1 = __builtin_amdgcn_cvt_f32_fp8(u, 1);
  float r2 = __builtin_amdgcn_cvt_f32_fp8(u, 2);
  float r3 = __builtin_amdgcn_cvt_f32_fp8(u, 3);
  float s = (r0 * r0 + r1 * r1) + (r2 * r2 + r3 * r3);
  int k0 = c32 << 2;                                 // logical k of byte 0
  int g  = (((k0 >> 3) & 3) << 2) | (k0 >> 5);       // granule index
  int p  = ((g ^ (row & 15)) << 3) + (k0 & 7);       // 4B-aligned
  *(uint32_t*)(zb + (size_t)row * DIMK + p) = (uint32_t)u;
  #pragma unroll
  for (int off = 16; off; off >>= 1) s += __shfl_down(s, off, 32);
  if (c32 == 0) sq[row] = s;
}

// One block = one 128x128 tile of z.z^T, upper triangle, off-diag weight 2x.
// 512 threads = 8 waves in 4x2 (wm 0..3 x wn 0..1); each wave 2x4 frags of
// 16x16x32 fp8_fp8. Tiles 16KB, staged once as a LINEAR copy (swizzle is
// baked into zb). Frag reads: ds_read_b64, conflict-free.
__global__ __launch_bounds__(512, 6) void loss_kernel(
    const unsigned char* __restrict__ zb, const float* __restrict__ sq,
    const int* __restrict__ labels, float* __restrict__ partials,
    unsigned int* __restrict__ counter, float* __restrict__ out) {
  __shared__ __align__(16) unsigned char ldsA[16384];
  __shared__ __align__(16) unsigned char ldsB[16384];
  __shared__ __align__(16) float sqAl[128];
  __shared__ __align__(16) float sqBl[128];
  __shared__ __align__(16) int   laAl[128];
  __shared__ __align__(16) int   laBl[128];
  __shared__ float red[8];
  __shared__ int lastFlag;

  int tid = threadIdx.x, lane = tid & 63, wave = tid >> 6;

  // ---- triangular decode: bid -> (bi, bj), bi <= bj ----
  int bid = blockIdx.x;
  #define TRI(rr) ((rr) * NB - ((rr) * ((rr) - 1)) / 2)
  int r = (int)(((float)(2 * NB + 1) -
                 sqrtf((float)((2 * NB + 1) * (2 * NB + 1) - 8 * bid))) * 0.5f);
  if (r < 0) r = 0; if (r > NB - 1) r = NB - 1;
  while (TRI(r + 1) <= bid) ++r;
  while (TRI(r) > bid) --r;
  int bi = r, bj = bid - TRI(r) + r;

  // ---- stage tiles: pure linear 16KB copies, 1024 chunks, 2 rounds ----
  const unsigned char* Ab = zb + (((size_t)bi << 7) * DIMK);
  const unsigned char* Bb = zb + (((size_t)bj << 7) * DIMK);
  #pragma unroll
  for (int t = 0; t < 2; ++t) {
    int L0 = (t << 9) + (wave << 6);                 // wave-uniform chunk base
    int L  = L0 + lane;
    __builtin_amdgcn_global_load_lds(
        (const AS_GLOBAL void*)(uintptr_t)(Ab + (size_t)L * 16),
        (AS_LDS void*)(uintptr_t)(ldsA + (size_t)L0 * 16), 16, 0, 0);
    __builtin_amdgcn_global_load_lds(
        (const AS_GLOBAL void*)(uintptr_t)(Bb + (size_t)L * 16),
        (AS_LDS void*)(uintptr_t)(ldsB + (size_t)L0 * 16), 16, 0, 0);
  }
  // ---- stage sq + labels for this block's rows/cols into LDS ----
  if (tid < 128) {
    sqAl[tid] = sq[(bi << 7) + tid];
    laAl[tid] = labels[(bi << 7) + tid];
  } else if (tid < 256) {
    int t2 = tid & 127;
    sqBl[t2] = sq[(bj << 7) + t2];
    laBl[t2] = labels[(bj << 7) + t2];
  }
  asm volatile("s_waitcnt vmcnt(0)" ::: "memory");
  __syncthreads();

  // ---- MFMA: per-ks b64 frag loads (6 live longs), 8 MFMAs per ks ----
  int wm = wave >> 1, wn = wave & 1;
  int lc = lane & 15;                                // frag row (A) / col (out)
  int q  = lane >> 4;                                // quad: k-granule select
  f32x4 acc[2][4] = {};
  #pragma unroll
  for (int ks = 0; ks < 4; ++ks) {
    int so = ((((q << 2) | ks) ^ lc) << 3);          // swizzled slot offset
    long a0 = *(const long*)(ldsA + ((wm << 5)      + lc) * 128 + so);
    long a1 = *(const long*)(ldsA + ((wm << 5) + 16 + lc) * 128 + so);
    long b0 = *(const long*)(ldsB + ((wn << 6)      + lc) * 128 + so);
    long b1 = *(const long*)(ldsB + ((wn << 6) + 16 + lc) * 128 + so);
    long b2 = *(const long*)(ldsB + ((wn << 6) + 32 + lc) * 128 + so);
    long b3 = *(const long*)(ldsB + ((wn << 6) + 48 + lc) * 128 + so);
    acc[0][0] = __builtin_amdgcn_mfma_f32_16x16x32_fp8_fp8(a0, b0, acc[0][0], 0, 0, 0);
    acc[0][1] = __builtin_amdgcn_mfma_f32_16x16x32_fp8_fp8(a0, b1, acc[0][1], 0, 0, 0);
    acc[0][2] = __builtin_amdgcn_mfma_f32_16x16x32_fp8_fp8(a0, b2, acc[0][2], 0, 0, 0);
    acc[0][3] = __builtin_amdgcn_mfma_f32_16x16x32_fp8_fp8(a0, b3, acc[0][3], 0, 0, 0);
    acc[1][0] = __builtin_amdgcn_mfma_f32_16x16x32_fp8_fp8(a1, b0, acc[1][0], 0, 0, 0);
    acc[1][1] = __builtin_amdgcn_mfma_f32_16x16x32_fp8_fp8(a1, b1, acc[1][1], 0, 0, 0);
    acc[1][2] = __builtin_amdgcn_mfma_f32_16x16x32_fp8_fp8(a1, b2, acc[1][2], 0, 0, 0);
    acc[1][3] = __builtin_amdgcn_mfma_f32_16x16x32_fp8_fp8(a1, b3, acc[1][3], 0, 0, 0);
  }

  // ---- epilogue: branchless fast pass + ONE deferred vote ----
  // C/D layout (shape-determined): col = lane&15, row = (lane>>4)*4 + reg.
  // If every d2 in this wave's outputs >= 1: non-eq term EXACTLY 0, eq term
  // exactly d2. Else (diagonal-touching waves only) redo on exact slow path.
  int r0 = q << 2;
  float sn_[4]; int ln_[4];
  #pragma unroll
  for (int j = 0; j < 4; ++j) {
    int n = (wn << 6) + (j << 4) + lc;
    sn_[j] = sqBl[n]; ln_[j] = laBl[n];
  }
  float ps0 = 0.f, ps1 = 0.f, ps2 = 0.f, ps3 = 0.f;
  float mnall = 1e30f;
  #pragma unroll
  for (int i = 0; i < 2; ++i) {
    int mb = (wm << 5) + (i << 4) + r0;
    f32x4 sm4 = *(const f32x4*)&sqAl[mb];
    int4  lm4 = *(const int4*)&laAl[mb];
    #pragma unroll
    for (int j = 0; j < 4; ++j) {
      float d0  = fmaf(-2.f, acc[i][j][0], sm4[0] + sn_[j]);
      float d1  = fmaf(-2.f, acc[i][j][1], sm4[1] + sn_[j]);
      float d2_ = fmaf(-2.f, acc[i][j][2], sm4[2] + sn_[j]);
      float d3  = fmaf(-2.f, acc[i][j][3], sm4[3] + sn_[j]);
      mnall = fminf(mnall, fminf(fminf(d0, d1), fminf(d2_, d3)));
      ps0 += (lm4.x == ln_[j]) ? d0  : 0.f;
      ps1 += (lm4.y == ln_[j]) ? d1  : 0.f;
      ps2 += (lm4.z == ln_[j]) ? d2_ : 0.f;
      ps3 += (lm4.w == ln_[j]) ? d3  : 0.f;
    }
  }
  if (__builtin_expect(__any(mnall < 1.f), 0)) {
    // exact slow path: recompute all outputs (acc still live)
    ps0 = ps1 = ps2 = ps3 = 0.f;
    #pragma unroll
    for (int i = 0; i < 2; ++i) {
      int mb = (wm << 5) + (i << 4) + r0;
      f32x4 sm4 = *(const f32x4*)&sqAl[mb];
      int4  lm4 = *(const int4*)&laAl[mb];
      #pragma unroll
      for (int j = 0; j < 4; ++j) {
        float dc, t;
        dc = fmaxf(fmaf(-2.f, acc[i][j][0], sm4[0] + sn_[j]), 0.f);
        t = fmaxf(1.f - sqrtf(dc), 0.f);
        ps0 += (lm4.x == ln_[j]) ? dc : t * t;
        dc = fmaxf(fmaf(-2.f, acc[i][j][1], sm4[1] + sn_[j]), 0.f);
        t = fmaxf(1.f - sqrtf(dc), 0.f);
        ps1 += (lm4.y == ln_[j]) ? dc : t * t;
        dc = fmaxf(fmaf(-2.f, acc[i][j][2], sm4[2] + sn_[j]), 0.f);
        t = fmaxf(1.f - sqrtf(dc), 0.f);
        ps2 += (lm4.z == ln_[j]) ? dc : t * t;
        dc = fmaxf(fmaf(-2.f, acc[i][j][3], sm4[3] + sn_[j]), 0.f);
        t = fmaxf(1.f - sqrtf(dc), 0.f);
        ps3 += (lm4.w == ln_[j]) ? dc : t * t;
      }
    }
  }
  float psum = (ps0 + ps1) + (ps2 + ps3);
  float w = (bi == bj) ? 1.f : 2.f;                  // symmetry weight
  psum *= w * (1.f / (8192.f * 8192.f));             // 2^-26, exact

  // ---- block reduction -> partials[bid]; ticket; last block sums all ----
  #pragma unroll
  for (int off = 32; off; off >>= 1) psum += __shfl_down(psum, off);
  if (lane == 0) red[wave] = psum;
  __syncthreads();
  if (tid == 0) {
    float s = 0.f;
    #pragma unroll
    for (int k = 0; k < 8; ++k) s += red[k];
    partials[bid] = s;
    __threadfence();                                 // partial visible first
    unsigned int tk = atomicAdd(counter, 1u);        // device-scope
    lastFlag = (tk == NBLK - 1);
  }
  __syncthreads();
  if (lastFlag) {
    __threadfence();                                 // acquire others' stores
    float s = 0.f;
    for (int k = tid; k < NBLK; k += 512) s += partials[k];
    #pragma unroll
    for (int off = 32; off; off >>= 1) s += __shfl_down(s, off);
    if (lane == 0) red[wave] = s;
    __syncthreads();
    if (tid == 0) {
      float t = 0.f;
      #pragma unroll
      for (int k = 0; k < 8; ++k) t += red[k];
      out[0] = t;
    }
  }
}

extern "C" void kernel_launch(void* const* d_in, const int* in_sizes, int n_in,
                              void* d_out, int out_size, void* d_ws, size_t ws_size,
                              hipStream_t stream) {
  const float* z      = (const float*)d_in[0];
  const int*   labels = (const int*)d_in[1];
  float*       out    = (float*)d_out;
  unsigned char* zb   = (unsigned char*)d_ws;                        // 1 MB
  char* p = (char*)d_ws + (size_t)NROWS * DIMK;
  float* sq             = (float*)p;                                 // 32 KB
  float* partials       = (float*)(p + NROWS * 4);                   // ~8 KB
  unsigned int* counter = (unsigned int*)(p + NROWS * 4 + NBLK * 4);

  prep_kernel<<<NROWS / 8, 256, 0, stream>>>(z, zb, sq, counter);
  loss_kernel<<<NBLK, 512, 0, stream>>>(zb, sq, labels, partials, counter, out);
}

// Round 7
// 73.849 us; speedup vs baseline: 2.5462x; 2.5462x over previous
//
#include <hip/hip_runtime.h>
#include <stdint.h>

// ContrastiveLoss: mean over all pairs of (same-label ? d2 : relu(1-dist)^2)
// z: [8192,128] fp32, labels: [8192] int32. Output: 1 fp32 scalar.
//
// R7: R6 minus the grid-wide ticket reduction. The per-block device-scope
// __threadfence() forced L2 writeback+invalidate on every one of 2080 blocks
// (per-XCD L2 non-coherent): 204 MB phantom WRITE_SIZE, 28 MB FETCH, 10x
// slowdown. Final reduction is a separate 2us kernel again (R4 pattern).
// Kept from R6 (verified by counters): baked granule swizzle -> LDS bank
// conflicts 0 (was 64 cyc/wave); linear global_load_lds staging; deferred
// single wave-vote epilogue; (512,6) -> 3 blocks/CU, no spill (40+32 regs).

#define NROWS 8192
#define DIMK  128
#define NB    64                     // 8192 / 128
#define NBLK  (NB * (NB + 1) / 2)    // 2080 upper-triangle blocks

typedef __attribute__((ext_vector_type(4))) float f32x4;

#define AS_GLOBAL __attribute__((address_space(1)))
#define AS_LDS    __attribute__((address_space(3)))

// Convert z -> fp8 e4m3 with granule-swizzled rows: logical k lives in
// granule g = ((k>>3)&3)<<2 | (k>>5) (the 8B MFMA operand for quad q, step
// ks), stored at byte pos ((g ^ (row&15)) << 3) + (k&7). Dot-invariant.
// Also: per-row sum of squares of ROUNDED values (diagonal d2 == 0 exactly).
__global__ __launch_bounds__(256) void prep_kernel(
    const float* __restrict__ z, unsigned char* __restrict__ zb,
    float* __restrict__ sq) {
  int tid = threadIdx.x;
  int row = (blockIdx.x << 3) + (tid >> 5);          // 8 rows per block
  int c32 = tid & 31;                                // 32 lanes per row
  float4 x = ((const float4*)(z + (size_t)row * DIMK))[c32];
  int u = __builtin_amdgcn_cvt_pk_fp8_f32(x.x, x.y, 0, false);
  u     = __builtin_amdgcn_cvt_pk_fp8_f32(x.z, x.w, u, true);
  float r0 = __builtin_amdgcn_cvt_f32_fp8(u, 0);
  float r1 = __builtin_amdgcn_cvt_f32_fp8(u, 1);
  float r2 = __builtin_amdgcn_cvt_f32_fp8(u, 2);
  float r3 = __builtin_amdgcn_cvt_f32_fp8(u, 3);
  float s = (r0 * r0 + r1 * r1) + (r2 * r2 + r3 * r3);
  int k0 = c32 << 2;                                 // logical k of byte 0
  int g  = (((k0 >> 3) & 3) << 2) | (k0 >> 5);       // granule index
  int p  = ((g ^ (row & 15)) << 3) + (k0 & 7);       // 4B-aligned
  *(uint32_t*)(zb + (size_t)row * DIMK + p) = (uint32_t)u;
  #pragma unroll
  for (int off = 16; off; off >>= 1) s += __shfl_down(s, off, 32);
  if (c32 == 0) sq[row] = s;
}

// One block = one 128x128 tile of z.z^T, upper triangle, off-diag weight 2x.
// 512 threads = 8 waves in 4x2 (wm 0..3 x wn 0..1); each wave 2x4 frags of
// 16x16x32 fp8_fp8. Tiles 16KB, staged once as a LINEAR copy (swizzle is
// baked into zb). Frag reads: ds_read_b64, conflict-free.
__global__ __launch_bounds__(512, 6) void loss_kernel(
    const unsigned char* __restrict__ zb, const float* __restrict__ sq,
    const int* __restrict__ labels, float* __restrict__ partials) {
  __shared__ __align__(16) unsigned char ldsA[16384];
  __shared__ __align__(16) unsigned char ldsB[16384];
  __shared__ __align__(16) float sqAl[128];
  __shared__ __align__(16) float sqBl[128];
  __shared__ __align__(16) int   laAl[128];
  __shared__ __align__(16) int   laBl[128];
  __shared__ float red[8];

  int tid = threadIdx.x, lane = tid & 63, wave = tid >> 6;

  // ---- triangular decode: bid -> (bi, bj), bi <= bj ----
  int bid = blockIdx.x;
  #define TRI(rr) ((rr) * NB - ((rr) * ((rr) - 1)) / 2)
  int r = (int)(((float)(2 * NB + 1) -
                 sqrtf((float)((2 * NB + 1) * (2 * NB + 1) - 8 * bid))) * 0.5f);
  if (r < 0) r = 0; if (r > NB - 1) r = NB - 1;
  while (TRI(r + 1) <= bid) ++r;
  while (TRI(r) > bid) --r;
  int bi = r, bj = bid - TRI(r) + r;

  // ---- stage tiles: pure linear 16KB copies, 1024 chunks, 2 rounds ----
  const unsigned char* Ab = zb + (((size_t)bi << 7) * DIMK);
  const unsigned char* Bb = zb + (((size_t)bj << 7) * DIMK);
  #pragma unroll
  for (int t = 0; t < 2; ++t) {
    int L0 = (t << 9) + (wave << 6);                 // wave-uniform chunk base
    int L  = L0 + lane;
    __builtin_amdgcn_global_load_lds(
        (const AS_GLOBAL void*)(uintptr_t)(Ab + (size_t)L * 16),
        (AS_LDS void*)(uintptr_t)(ldsA + (size_t)L0 * 16), 16, 0, 0);
    __builtin_amdgcn_global_load_lds(
        (const AS_GLOBAL void*)(uintptr_t)(Bb + (size_t)L * 16),
        (AS_LDS void*)(uintptr_t)(ldsB + (size_t)L0 * 16), 16, 0, 0);
  }
  // ---- stage sq + labels for this block's rows/cols into LDS ----
  if (tid < 128) {
    sqAl[tid] = sq[(bi << 7) + tid];
    laAl[tid] = labels[(bi << 7) + tid];
  } else if (tid < 256) {
    int t2 = tid & 127;
    sqBl[t2] = sq[(bj << 7) + t2];
    laBl[t2] = labels[(bj << 7) + t2];
  }
  asm volatile("s_waitcnt vmcnt(0)" ::: "memory");
  __syncthreads();

  // ---- MFMA: per-ks b64 frag loads (6 live longs), 8 MFMAs per ks ----
  int wm = wave >> 1, wn = wave & 1;
  int lc = lane & 15;                                // frag row (A) / col (out)
  int q  = lane >> 4;                                // quad: k-granule select
  f32x4 acc[2][4] = {};
  #pragma unroll
  for (int ks = 0; ks < 4; ++ks) {
    int so = ((((q << 2) | ks) ^ lc) << 3);          // swizzled slot offset
    long a0 = *(const long*)(ldsA + ((wm << 5)      + lc) * 128 + so);
    long a1 = *(const long*)(ldsA + ((wm << 5) + 16 + lc) * 128 + so);
    long b0 = *(const long*)(ldsB + ((wn << 6)      + lc) * 128 + so);
    long b1 = *(const long*)(ldsB + ((wn << 6) + 16 + lc) * 128 + so);
    long b2 = *(const long*)(ldsB + ((wn << 6) + 32 + lc) * 128 + so);
    long b3 = *(const long*)(ldsB + ((wn << 6) + 48 + lc) * 128 + so);
    acc[0][0] = __builtin_amdgcn_mfma_f32_16x16x32_fp8_fp8(a0, b0, acc[0][0], 0, 0, 0);
    acc[0][1] = __builtin_amdgcn_mfma_f32_16x16x32_fp8_fp8(a0, b1, acc[0][1], 0, 0, 0);
    acc[0][2] = __builtin_amdgcn_mfma_f32_16x16x32_fp8_fp8(a0, b2, acc[0][2], 0, 0, 0);
    acc[0][3] = __builtin_amdgcn_mfma_f32_16x16x32_fp8_fp8(a0, b3, acc[0][3], 0, 0, 0);
    acc[1][0] = __builtin_amdgcn_mfma_f32_16x16x32_fp8_fp8(a1, b0, acc[1][0], 0, 0, 0);
    acc[1][1] = __builtin_amdgcn_mfma_f32_16x16x32_fp8_fp8(a1, b1, acc[1][1], 0, 0, 0);
    acc[1][2] = __builtin_amdgcn_mfma_f32_16x16x32_fp8_fp8(a1, b2, acc[1][2], 0, 0, 0);
    acc[1][3] = __builtin_amdgcn_mfma_f32_16x16x32_fp8_fp8(a1, b3, acc[1][3], 0, 0, 0);
  }

  // ---- epilogue: branchless fast pass + ONE deferred vote ----
  // C/D layout (shape-determined): col = lane&15, row = (lane>>4)*4 + reg.
  // If every d2 in this wave's outputs >= 1: non-eq term EXACTLY 0, eq term
  // exactly d2. Else (diagonal-touching waves only) redo on exact slow path.
  int r0 = q << 2;
  float sn_[4]; int ln_[4];
  #pragma unroll
  for (int j = 0; j < 4; ++j) {
    int n = (wn << 6) + (j << 4) + lc;
    sn_[j] = sqBl[n]; ln_[j] = laBl[n];
  }
  float ps0 = 0.f, ps1 = 0.f, ps2 = 0.f, ps3 = 0.f;
  float mnall = 1e30f;
  #pragma unroll
  for (int i = 0; i < 2; ++i) {
    int mb = (wm << 5) + (i << 4) + r0;
    f32x4 sm4 = *(const f32x4*)&sqAl[mb];
    int4  lm4 = *(const int4*)&laAl[mb];
    #pragma unroll
    for (int j = 0; j < 4; ++j) {
      float d0  = fmaf(-2.f, acc[i][j][0], sm4[0] + sn_[j]);
      float d1  = fmaf(-2.f, acc[i][j][1], sm4[1] + sn_[j]);
      float d2_ = fmaf(-2.f, acc[i][j][2], sm4[2] + sn_[j]);
      float d3  = fmaf(-2.f, acc[i][j][3], sm4[3] + sn_[j]);
      mnall = fminf(mnall, fminf(fminf(d0, d1), fminf(d2_, d3)));
      ps0 += (lm4.x == ln_[j]) ? d0  : 0.f;
      ps1 += (lm4.y == ln_[j]) ? d1  : 0.f;
      ps2 += (lm4.z == ln_[j]) ? d2_ : 0.f;
      ps3 += (lm4.w == ln_[j]) ? d3  : 0.f;
    }
  }
  if (__builtin_expect(__any(mnall < 1.f), 0)) {
    // exact slow path: recompute all outputs (acc still live)
    ps0 = ps1 = ps2 = ps3 = 0.f;
    #pragma unroll
    for (int i = 0; i < 2; ++i) {
      int mb = (wm << 5) + (i << 4) + r0;
      f32x4 sm4 = *(const f32x4*)&sqAl[mb];
      int4  lm4 = *(const int4*)&laAl[mb];
      #pragma unroll
      for (int j = 0; j < 4; ++j) {
        float dc, t;
        dc = fmaxf(fmaf(-2.f, acc[i][j][0], sm4[0] + sn_[j]), 0.f);
        t = fmaxf(1.f - sqrtf(dc), 0.f);
        ps0 += (lm4.x == ln_[j]) ? dc : t * t;
        dc = fmaxf(fmaf(-2.f, acc[i][j][1], sm4[1] + sn_[j]), 0.f);
        t = fmaxf(1.f - sqrtf(dc), 0.f);
        ps1 += (lm4.y == ln_[j]) ? dc : t * t;
        dc = fmaxf(fmaf(-2.f, acc[i][j][2], sm4[2] + sn_[j]), 0.f);
        t = fmaxf(1.f - sqrtf(dc), 0.f);
        ps2 += (lm4.z == ln_[j]) ? dc : t * t;
        dc = fmaxf(fmaf(-2.f, acc[i][j][3], sm4[3] + sn_[j]), 0.f);
        t = fmaxf(1.f - sqrtf(dc), 0.f);
        ps3 += (lm4.w == ln_[j]) ? dc : t * t;
      }
    }
  }
  float psum = (ps0 + ps1) + (ps2 + ps3);
  float w = (bi == bj) ? 1.f : 2.f;                  // symmetry weight
  psum *= w * (1.f / (8192.f * 8192.f));             // 2^-26, exact

  // ---- block reduction -> partials[bid] (plain store, no fences) ----
  #pragma unroll
  for (int off = 32; off; off >>= 1) psum += __shfl_down(psum, off);
  if (lane == 0) red[wave] = psum;
  __syncthreads();
  if (tid == 0) {
    float s = 0.f;
    #pragma unroll
    for (int k = 0; k < 8; ++k) s += red[k];
    partials[bid] = s;
  }
}

// Sum NBLK partials -> out[0]. One block.
__global__ __launch_bounds__(256) void reduce_kernel(
    const float* __restrict__ partials, float* __restrict__ out) {
  int tid = threadIdx.x, lane = tid & 63, wave = tid >> 6;
  float s = 0.f;
  for (int k = tid; k < NBLK; k += 256) s += partials[k];
  #pragma unroll
  for (int off = 32; off; off >>= 1) s += __shfl_down(s, off);
  __shared__ float red[4];
  if (lane == 0) red[wave] = s;
  __syncthreads();
  if (tid == 0) out[0] = red[0] + red[1] + red[2] + red[3];
}

extern "C" void kernel_launch(void* const* d_in, const int* in_sizes, int n_in,
                              void* d_out, int out_size, void* d_ws, size_t ws_size,
                              hipStream_t stream) {
  const float* z      = (const float*)d_in[0];
  const int*   labels = (const int*)d_in[1];
  float*       out    = (float*)d_out;
  unsigned char* zb   = (unsigned char*)d_ws;                        // 1 MB
  char* p = (char*)d_ws + (size_t)NROWS * DIMK;
  float* sq       = (float*)p;                                       // 32 KB
  float* partials = (float*)(p + NROWS * 4);                         // ~8 KB

  prep_kernel<<<NROWS / 8, 256, 0, stream>>>(z, zb, sq);
  loss_kernel<<<NBLK, 512, 0, stream>>>(zb, sq, labels, partials);
  reduce_kernel<<<1, 256, 0, stream>>>(partials, out);
}